// Round 11
// baseline (181.277 us; speedup 1.0000x reference)
//
#include <hip/hip_runtime.h>
#include <stdint.h>

#define N_V 100000
#define N_E 200000
#define NNZ 800000
#define D_IN 14
#define H 128

#define RSH 9             // row bucket = 512 vertices
#define CSH 10            // col bucket = 1024 edges
#define NB 196            // ceil(100000/512) = ceil(200000/1024) = 196
#define CAPR 6144
#define CAPC 6144
#define VMASK 0x3FFFFu

// ---------------- single-pass merged bin (both directions) + fusew rider blocks ----------------
__global__ __launch_bounds__(1024) void k_bin2(const int* __restrict__ rows, const int* __restrict__ cols,
                                               const float* __restrict__ W0, const float* __restrict__ b0,
                                               const float* __restrict__ Wl0, const float* __restrict__ bl0,
                                               float* __restrict__ W0f, float* __restrict__ b0f,
                                               unsigned* __restrict__ binnedR, int* __restrict__ cntR,
                                               unsigned* __restrict__ binnedC, int* __restrict__ cntC) {
  int t = threadIdx.x;
  if (blockIdx.x >= NB) {           // fusew rider: W0f = W0@Wl0, b0f = b0@Wl0 + bl0
    if (t < 128) {
      int n = t, d = blockIdx.x - NB;
      if (d < D_IN) {
        float acc = 0.f;
        for (int k = 0; k < H; k++) acc += W0[d * H + k] * Wl0[k * H + n];
        W0f[d * H + n] = acc;
      } else {
        float accb = bl0[n];
        for (int k = 0; k < H; k++) accb += b0[k] * Wl0[k * H + n];
        b0f[n] = accb;
      }
    }
    return;
  }
  // layout: index [0,256) = R-buckets, [256,512) = C-buckets
  __shared__ int bcnt[512], bsc[512], bex[512], gb[512];
  __shared__ unsigned recsR[4096], recsC[4096];
  __shared__ unsigned short bidR[4096], bidC[4096];
  int r_[4], c_[4], lpR[4], lpC[4], bR[4], bC[4];
  int base = blockIdx.x * 4096;
#pragma unroll
  for (int u = 0; u < 4; u++) {
    int i = base + u * 1024 + t;
    if (i < NNZ) { r_[u] = rows[i]; c_[u] = cols[i]; } else r_[u] = -1;
  }
  if (t < 512) bcnt[t] = 0;
  __syncthreads();
  // concurrent histograms (R and C)
#pragma unroll
  for (int u = 0; u < 4; u++) {
    if (r_[u] >= 0) {
      bR[u] = r_[u] >> RSH;        lpR[u] = atomicAdd(&bcnt[bR[u]], 1);
      bC[u] = c_[u] >> CSH;        lpC[u] = atomicAdd(&bcnt[256 + bC[u]], 1);
    } else { bR[u] = -1; }
  }
  __syncthreads();
  if (t < 512) bsc[t] = bcnt[t];
  __syncthreads();
  // halved Hillis-Steele scan: each 256-entry half scans independently
  for (int o = 1; o < 256; o <<= 1) {
    int x = (t < 512 && (t & 255) >= o) ? bsc[t - o] : 0;
    __syncthreads();
    if (t < 512) bsc[t] += x;
    __syncthreads();
  }
  if (t < 512) bex[t] = bsc[t] - bcnt[t];
  __syncthreads();
  // place both record sets in LDS
#pragma unroll
  for (int u = 0; u < 4; u++) {
    if (bR[u] >= 0) {
      int pR = bex[bR[u]] + lpR[u];
      recsR[pR] = ((unsigned)(r_[u] & 511) << 18) | (unsigned)c_[u];
      bidR[pR] = (unsigned short)bR[u];
      int pC = bex[256 + bC[u]] + lpC[u];
      recsC[pC] = ((unsigned)(c_[u] & 1023) << 18) | (unsigned)r_[u];
      bidC[pC] = (unsigned short)bC[u];
    }
  }
  // global base allocation for both directions
  if (t < NB && bcnt[t] > 0) gb[t] = t * CAPR + atomicAdd(&cntR[t], bcnt[t]);
  if (t >= 256 && t < 256 + NB && bcnt[t] > 0) gb[t] = (t - 256) * CAPC + atomicAdd(&cntC[t - 256], bcnt[t]);
  __syncthreads();
  int totR = bsc[255], totC = bsc[511];
  for (int p = t; p < totR; p += 1024) {
    int b = bidR[p];
    binnedR[gb[b] + (p - bex[b])] = recsR[p];
  }
  for (int p = t; p < totC; p += 1024) {
    int b = bidC[p];
    binnedC[gb[256 + b] + (p - bex[256 + b])] = recsC[p];
  }
}

// ---------------- P0: vertex degree -> rdegf, invdg (256 thr, 16-deep MLP) ----------------
__global__ __launch_bounds__(256) void k_p0(const unsigned* __restrict__ binnedR, const int* __restrict__ cntR,
                                            float* __restrict__ rdegf, float* __restrict__ invdg) {
  __shared__ int ideg[512];
  int t = threadIdx.x, b = blockIdx.x;
  ideg[t] = 0; ideg[t + 256] = 0;
  __syncthreads();
  int cnt = cntR[b];
  const unsigned* rec = binnedR + (size_t)b * CAPR;
  int p = t;
  for (; p + 3840 < cnt; p += 4096) {
    unsigned a[16];
#pragma unroll
    for (int j = 0; j < 16; j++) a[j] = rec[p + j * 256];
#pragma unroll
    for (int j = 0; j < 16; j++) atomicAdd(&ideg[a[j] >> 18], 1);
  }
  for (; p < cnt; p += 256) atomicAdd(&ideg[rec[p] >> 18], 1);
  __syncthreads();
#pragma unroll
  for (int j = 0; j < 2; j++) {
    int s = t + j * 256;
    int v = (b << RSH) + s;
    if (v < N_V) {
      int d = ideg[s];
      rdegf[v] = (float)d;
      invdg[v] = 1.f / (float)(d > 0 ? d : 1);
    }
  }
}

// ---------------- P1: per-edge (w, n) (256 thr, 16-deep MLP) ----------------
__global__ __launch_bounds__(256) void k_p1(const unsigned* __restrict__ binnedC, const int* __restrict__ cntC,
                                            const float* __restrict__ invdg, float2* __restrict__ wn) {
  __shared__ int n_l[1024];
  __shared__ float w_l[1024];
  int t = threadIdx.x, b = blockIdx.x;
#pragma unroll
  for (int j = 0; j < 4; j++) { n_l[t + j * 256] = 0; w_l[t + j * 256] = 0.f; }
  __syncthreads();
  int cnt = cntC[b];
  const unsigned* rec = binnedC + (size_t)b * CAPC;
  int p = t;
  for (; p + 3840 < cnt; p += 4096) {
    unsigned a[16];
    float iv[16];
#pragma unroll
    for (int j = 0; j < 16; j++) a[j] = rec[p + j * 256];
#pragma unroll
    for (int j = 0; j < 16; j++) iv[j] = invdg[a[j] & VMASK];
#pragma unroll
    for (int j = 0; j < 16; j++) {
      atomicAdd(&n_l[a[j] >> 18], 1);
      atomicAdd(&w_l[a[j] >> 18], iv[j]);
    }
  }
  for (; p < cnt; p += 256) {
    unsigned a0 = rec[p];
    atomicAdd(&n_l[a0 >> 18], 1);
    atomicAdd(&w_l[a0 >> 18], invdg[a0 & VMASK]);
  }
  __syncthreads();
#pragma unroll
  for (int j = 0; j < 4; j++) {
    int s = t + j * 256;
    int e = (b << CSH) + s;
    if (e < N_E) wn[e] = make_float2(w_l[s], (float)n_l[s]);
  }
}

// ---------------- P2: Wv, Sv, WvD (256 thr, 16-deep MLP) ----------------
__global__ __launch_bounds__(256) void k_p2(const unsigned* __restrict__ binnedR, const int* __restrict__ cntR,
                                            const float2* __restrict__ wn, const float* __restrict__ invdg,
                                            float* __restrict__ Wv, float* __restrict__ Sv,
                                            float* __restrict__ WvD) {
  __shared__ float W_l[512], S_l[512];
  int t = threadIdx.x, b = blockIdx.x;
  W_l[t] = 0.f; W_l[t + 256] = 0.f; S_l[t] = 0.f; S_l[t + 256] = 0.f;
  __syncthreads();
  int cnt = cntR[b];
  const unsigned* rec = binnedR + (size_t)b * CAPR;
  int p = t;
  for (; p + 3840 < cnt; p += 4096) {
    unsigned a[16];
    float2 w[16];
#pragma unroll
    for (int j = 0; j < 16; j++) a[j] = rec[p + j * 256];
#pragma unroll
    for (int j = 0; j < 16; j++) w[j] = wn[a[j] & VMASK];
#pragma unroll
    for (int j = 0; j < 16; j++) {
      atomicAdd(&W_l[a[j] >> 18], w[j].x);
      atomicAdd(&S_l[a[j] >> 18], w[j].y);
    }
  }
  for (; p < cnt; p += 256) {
    unsigned a0 = rec[p];
    float2 w0 = wn[a0 & VMASK];
    atomicAdd(&W_l[a0 >> 18], w0.x); atomicAdd(&S_l[a0 >> 18], w0.y);
  }
  __syncthreads();
#pragma unroll
  for (int j = 0; j < 2; j++) {
    int s = t + j * 256;
    int v = (b << RSH) + s;
    if (v < N_V) {
      float W = W_l[s];
      Wv[v] = W; Sv[v] = S_l[s]; WvD[v] = W * invdg[v];
    }
  }
}

// ---------------- P3: z[e] = sum WvD over edge members (256 thr, 16-deep MLP) ----------------
__global__ __launch_bounds__(256) void k_p3(const unsigned* __restrict__ binnedC, const int* __restrict__ cntC,
                                            const float* __restrict__ WvD, float* __restrict__ zM) {
  __shared__ float z_l[1024];
  int t = threadIdx.x, b = blockIdx.x;
#pragma unroll
  for (int j = 0; j < 4; j++) z_l[t + j * 256] = 0.f;
  __syncthreads();
  int cnt = cntC[b];
  const unsigned* rec = binnedC + (size_t)b * CAPC;
  int p = t;
  for (; p + 3840 < cnt; p += 4096) {
    unsigned a[16];
    float v[16];
#pragma unroll
    for (int j = 0; j < 16; j++) a[j] = rec[p + j * 256];
#pragma unroll
    for (int j = 0; j < 16; j++) v[j] = WvD[a[j] & VMASK];
#pragma unroll
    for (int j = 0; j < 16; j++) atomicAdd(&z_l[a[j] >> 18], v[j]);
  }
  for (; p < cnt; p += 256) {
    unsigned a0 = rec[p];
    atomicAdd(&z_l[a0 >> 18], WvD[a0 & VMASK]);
  }
  __syncthreads();
#pragma unroll
  for (int j = 0; j < 4; j++) {
    int s = t + j * 256;
    int e = (b << CSH) + s;
    if (e < N_E) zM[e] = z_l[s];
  }
}

// ---------------- P4: Z2 (LDS) + 4 weighted X column-sums ----------------
__global__ __launch_bounds__(1024) void k_p4(const unsigned* __restrict__ binnedR, const int* __restrict__ cntR,
                                             const float* __restrict__ zM,
                                             const float* __restrict__ rdegf, const float* __restrict__ Wv,
                                             const float* __restrict__ Sv, const float* __restrict__ X,
                                             float* __restrict__ swg) {
  __shared__ float Z_l[512];
  __shared__ float swl[64];
  int t = threadIdx.x, b = blockIdx.x;
  if (t < 512) Z_l[t] = 0.f;
  if (t < 64) swl[t] = 0.f;
  __syncthreads();
  int cnt = cntR[b];
  const unsigned* rec = binnedR + (size_t)b * CAPR;
  int p = t;
  for (; p + 3072 < cnt; p += 4096) {
    unsigned a0 = rec[p], a1 = rec[p + 1024], a2 = rec[p + 2048], a3 = rec[p + 3072];
    float v0 = zM[a0 & VMASK], v1 = zM[a1 & VMASK];
    float v2 = zM[a2 & VMASK], v3 = zM[a3 & VMASK];
    atomicAdd(&Z_l[a0 >> 18], v0); atomicAdd(&Z_l[a1 >> 18], v1);
    atomicAdd(&Z_l[a2 >> 18], v2); atomicAdd(&Z_l[a3 >> 18], v3);
  }
  for (; p < cnt; p += 1024) {
    unsigned a0 = rec[p];
    atomicAdd(&Z_l[a0 >> 18], zM[a0 & VMASK]);
  }
  __syncthreads();
  {
    int tv = t >> 1, h = t & 1;         // thread = (vertex-in-bin, half-of-dims)
    int v = (b << RSH) + tv;
    float ps0[8] = {0,0,0,0,0,0,0,0}, ps1[8] = {0,0,0,0,0,0,0,0};
    float ps2[8] = {0,0,0,0,0,0,0,0}, ps3[8] = {0,0,0,0,0,0,0,0};
    if (v < N_V) {
      float w1 = Wv[v];
      float w2 = rdegf[v] + Sv[v];
      float w3 = w1 + Z_l[tv];
      const float* xp = X + (size_t)v * D_IN + h * 7;
#pragma unroll
      for (int j = 0; j < 7; j++) {
        float xv = xp[j];
        ps0[j] += xv; ps1[j] += w1 * xv; ps2[j] += w2 * xv; ps3[j] += w3 * xv;
      }
      if (h) { ps0[7] = 1.f; ps1[7] = w1; ps2[7] = w2; ps3[7] = w3; }  // weight totals
    }
#pragma unroll
    for (int j = 0; j < 8; j++) {
      float v0 = ps0[j], v1 = ps1[j], v2 = ps2[j], v3 = ps3[j];
#pragma unroll
      for (int off = 2; off < 64; off <<= 1) {   // butterfly over same-h lanes
        v0 += __shfl_xor(v0, off); v1 += __shfl_xor(v1, off);
        v2 += __shfl_xor(v2, off); v3 += __shfl_xor(v3, off);
      }
      int lane = t & 63;
      if (lane < 2) {                   // lane 0: h=0 sums, lane 1: h=1 sums
        int s = lane * 8 + j;
        atomicAdd(&swl[0 * 16 + s], v0);
        atomicAdd(&swl[1 * 16 + s], v1);
        atomicAdd(&swl[2 * 16 + s], v2);
        atomicAdd(&swl[3 * 16 + s], v3);
      }
    }
  }
  __syncthreads();
  if (t < 64) atomicAdd(&swg[t], swl[t]);
}

// ---------------- P5: project 4x14 sums through W0f, push Wl1, output heads ----------------
__global__ __launch_bounds__(128) void k_p5(const float* __restrict__ swg,
                                            const float* __restrict__ W0f, const float* __restrict__ b0f,
                                            const float* __restrict__ Wl1, const float* __restrict__ bl1,
                                            const float* __restrict__ Wo0, const float* __restrict__ bo0,
                                            const float* __restrict__ Wo1, const float* __restrict__ bo1,
                                            float* __restrict__ out) {
  __shared__ float swl[64];
  __shared__ float fA[128], fB[128], redl[128];
  int t = threadIdx.x;
  if (t < 64) swl[t] = swg[t];
  __syncthreads();
  {
    float a_ = 0.f, e_ = 0.f;
#pragma unroll
    for (int j = 0; j < D_IN; j++) {
      int s = j < 7 ? j : j + 1;        // swl layout: [0..6]=dims0-6, [8..14]=dims7-13, [15]=sum w
      float w0 = W0f[j * H + t];
      a_ += (swl[s] + swl[16 + s] + swl[48 + s]) * w0;   // cs0+cs1+cs3
      e_ += swl[32 + s] * w0;                            // cs2
    }
    float S0 = swl[15], S1 = swl[31], S2 = swl[47], S3 = swl[63];
    float bb_ = b0f[t];
    a_ += (S0 + S1 + S3) * bb_;
    e_ += S2 * bb_;
    fA[t] = a_;
    fB[t] = e_;
  }
  __syncthreads();
  {
    float sx = 0.f, se = 0.f;
    for (int k = 0; k < H; k++) {
      float wv = Wl1[k * H + t];
      sx += fA[k] * wv;
      se += fB[k] * wv;
    }
    float Q = swl[31];                  // sum_v Wv == qsum
    sx += ((float)N_V + Q) * bl1[t];
    se += (float)NNZ * bl1[t];
    redl[t] = sx * (1.f / (float)N_V) * Wo0[t] + se * (1.f / (float)N_E) * Wo1[t];
  }
  __syncthreads();
  for (int o = 64; o > 0; o >>= 1) {
    if (t < o) redl[t] += redl[t + o];
    __syncthreads();
  }
  if (t == 0) out[0] = redl[0] + bo0[0] + bo1[0];
}

extern "C" void kernel_launch(void* const* d_in, const int* in_sizes, int n_in,
                              void* d_out, int out_size, void* d_ws, size_t ws_size,
                              hipStream_t stream) {
  const float* x0in = (const float*)d_in[0];
  const int* rows   = (const int*)d_in[2];
  const int* cols   = (const int*)d_in[3];
  const float* W0   = (const float*)d_in[4];
  const float* b0   = (const float*)d_in[5];
  const float* Wl0  = (const float*)d_in[8];
  const float* bl0  = (const float*)d_in[9];
  const float* Wl1  = (const float*)d_in[10];
  const float* bl1  = (const float*)d_in[11];
  const float* Wo0  = (const float*)d_in[12];
  const float* bo0  = (const float*)d_in[13];
  const float* Wo1  = (const float*)d_in[14];
  const float* bo1  = (const float*)d_in[15];
  float* out = (float*)d_out;
  char* ws = (char*)d_ws;

  // ---- workspace layout (only [0, 4096) needs zeroing) ----
  int*      cntR    = (int*)(ws + 0);            // 196 ints (pad 1024)
  int*      cntC    = (int*)(ws + 1024);         // 196 ints (pad 1024)
  float*    swg     = (float*)(ws + 2048);       // 64 floats
  float*    W0f     = (float*)(ws + 4096);       // 7,168
  float*    b0f     = (float*)(ws + 11264);      // 512
  float*    invdg   = (float*)(ws + 12288);      // 400,000
  float*    rdegf   = (float*)(ws + 412288);     // 400,000
  float*    Wv      = (float*)(ws + 812288);     // 400,000
  float*    Sv      = (float*)(ws + 1212288);    // 400,000
  float*    WvD     = (float*)(ws + 1612288);    // 400,000
  float2*   wn      = (float2*)(ws + 2012288);   // 1,600,000
  float*    zM      = (float*)(ws + 3612288);    // 800,000
  unsigned* binnedR = (unsigned*)(ws + 4412288); // 196*6144*4 = 4,816,896
  unsigned* binnedC = (unsigned*)(ws + 9229184); // 4,816,896
  // total: 14,046,080 B

  hipMemsetAsync(ws, 0, 4096, stream);
  k_bin2<<<dim3(NB + D_IN + 1), dim3(1024), 0, stream>>>(rows, cols, W0, b0, Wl0, bl0,
                                                         W0f, b0f, binnedR, cntR, binnedC, cntC);
  k_p0<<<dim3(NB), dim3(256), 0, stream>>>(binnedR, cntR, rdegf, invdg);
  k_p1<<<dim3(NB), dim3(256), 0, stream>>>(binnedC, cntC, invdg, wn);
  k_p2<<<dim3(NB), dim3(256), 0, stream>>>(binnedR, cntR, wn, invdg, Wv, Sv, WvD);
  k_p3<<<dim3(NB), dim3(256), 0, stream>>>(binnedC, cntC, WvD, zM);
  k_p4<<<dim3(NB), dim3(1024), 0, stream>>>(binnedR, cntR, zM, rdegf, Wv, Sv, x0in, swg);
  k_p5<<<dim3(1), dim3(128), 0, stream>>>(swg, W0f, b0f, Wl1, bl1, Wo0, bo0, Wo1, bo1, out);
}

// Round 12
// 162.803 us; speedup vs baseline: 1.1135x; 1.1135x over previous
//
#include <hip/hip_runtime.h>
#include <stdint.h>

#define N_V 100000
#define N_E 200000
#define NNZ 800000
#define D_IN 14
#define H 128

#define RSH 9             // row bucket = 512 vertices
#define CSH 10            // col bucket = 1024 edges
#define NB 196            // ceil(100000/512) = ceil(200000/1024) = 196
#define CAPR 6144
#define CAPC 6144
#define VMASK 0x3FFFFu

// ---------------- single-pass merged bin (both directions) + fusew rider blocks ----------------
__global__ __launch_bounds__(1024) void k_bin2(const int* __restrict__ rows, const int* __restrict__ cols,
                                               const float* __restrict__ W0, const float* __restrict__ b0,
                                               const float* __restrict__ Wl0, const float* __restrict__ bl0,
                                               float* __restrict__ W0f, float* __restrict__ b0f,
                                               unsigned* __restrict__ binnedR, int* __restrict__ cntR,
                                               unsigned* __restrict__ binnedC, int* __restrict__ cntC) {
  int t = threadIdx.x;
  if (blockIdx.x >= NB) {           // fusew rider: W0f = W0@Wl0, b0f = b0@Wl0 + bl0
    if (t < 128) {
      int n = t, d = blockIdx.x - NB;
      if (d < D_IN) {
        float acc = 0.f;
        for (int k = 0; k < H; k++) acc += W0[d * H + k] * Wl0[k * H + n];
        W0f[d * H + n] = acc;
      } else {
        float accb = bl0[n];
        for (int k = 0; k < H; k++) accb += b0[k] * Wl0[k * H + n];
        b0f[n] = accb;
      }
    }
    return;
  }
  // layout: index [0,256) = R-buckets, [256,512) = C-buckets
  __shared__ int bcnt[512], bsc[512], bex[512], gb[512];
  __shared__ unsigned recsR[4096], recsC[4096];
  __shared__ unsigned short bidR[4096], bidC[4096];
  int r_[4], c_[4], lpR[4], lpC[4], bR[4], bC[4];
  int base = blockIdx.x * 4096;
#pragma unroll
  for (int u = 0; u < 4; u++) {
    int i = base + u * 1024 + t;
    if (i < NNZ) { r_[u] = rows[i]; c_[u] = cols[i]; } else r_[u] = -1;
  }
  if (t < 512) bcnt[t] = 0;
  __syncthreads();
  // concurrent histograms (R and C)
#pragma unroll
  for (int u = 0; u < 4; u++) {
    if (r_[u] >= 0) {
      bR[u] = r_[u] >> RSH;        lpR[u] = atomicAdd(&bcnt[bR[u]], 1);
      bC[u] = c_[u] >> CSH;        lpC[u] = atomicAdd(&bcnt[256 + bC[u]], 1);
    } else { bR[u] = -1; }
  }
  __syncthreads();
  if (t < 512) bsc[t] = bcnt[t];
  __syncthreads();
  // halved Hillis-Steele scan: each 256-entry half scans independently
  for (int o = 1; o < 256; o <<= 1) {
    int x = (t < 512 && (t & 255) >= o) ? bsc[t - o] : 0;
    __syncthreads();
    if (t < 512) bsc[t] += x;
    __syncthreads();
  }
  if (t < 512) bex[t] = bsc[t] - bcnt[t];
  __syncthreads();
  // place both record sets in LDS
#pragma unroll
  for (int u = 0; u < 4; u++) {
    if (bR[u] >= 0) {
      int pR = bex[bR[u]] + lpR[u];
      recsR[pR] = ((unsigned)(r_[u] & 511) << 18) | (unsigned)c_[u];
      bidR[pR] = (unsigned short)bR[u];
      int pC = bex[256 + bC[u]] + lpC[u];
      recsC[pC] = ((unsigned)(c_[u] & 1023) << 18) | (unsigned)r_[u];
      bidC[pC] = (unsigned short)bC[u];
    }
  }
  // global base allocation for both directions
  if (t < NB && bcnt[t] > 0) gb[t] = t * CAPR + atomicAdd(&cntR[t], bcnt[t]);
  if (t >= 256 && t < 256 + NB && bcnt[t] > 0) gb[t] = (t - 256) * CAPC + atomicAdd(&cntC[t - 256], bcnt[t]);
  __syncthreads();
  int totR = bsc[255], totC = bsc[511];
  for (int p = t; p < totR; p += 1024) {
    int b = bidR[p];
    binnedR[gb[b] + (p - bex[b])] = recsR[p];
  }
  for (int p = t; p < totC; p += 1024) {
    int b = bidC[p];
    binnedC[gb[256 + b] + (p - bex[256 + b])] = recsC[p];
  }
}

// ---------------- P0: vertex degree -> rdegf, invdg ----------------
__global__ __launch_bounds__(1024) void k_p0(const unsigned* __restrict__ binnedR, const int* __restrict__ cntR,
                                             float* __restrict__ rdegf, float* __restrict__ invdg) {
  __shared__ int ideg[512];
  int t = threadIdx.x, b = blockIdx.x;
  if (t < 512) ideg[t] = 0;
  __syncthreads();
  int cnt = cntR[b];
  const unsigned* rec = binnedR + (size_t)b * CAPR;
  int p = t;
  for (; p + 3072 < cnt; p += 4096) {
    unsigned a0 = rec[p], a1 = rec[p + 1024], a2 = rec[p + 2048], a3 = rec[p + 3072];
    atomicAdd(&ideg[a0 >> 18], 1); atomicAdd(&ideg[a1 >> 18], 1);
    atomicAdd(&ideg[a2 >> 18], 1); atomicAdd(&ideg[a3 >> 18], 1);
  }
  for (; p < cnt; p += 1024) atomicAdd(&ideg[rec[p] >> 18], 1);
  __syncthreads();
  if (t < 512) {
    int v = (b << RSH) + t;
    if (v < N_V) {
      int d = ideg[t];
      rdegf[v] = (float)d;
      invdg[v] = 1.f / (float)(d > 0 ? d : 1);
    }
  }
}

// ---------------- P1: per-edge (w, n) ----------------
__global__ __launch_bounds__(1024) void k_p1(const unsigned* __restrict__ binnedC, const int* __restrict__ cntC,
                                             const float* __restrict__ invdg, float2* __restrict__ wn) {
  __shared__ int n_l[1024];
  __shared__ float w_l[1024];
  int t = threadIdx.x, b = blockIdx.x;
  n_l[t] = 0; w_l[t] = 0.f;
  __syncthreads();
  int cnt = cntC[b];
  const unsigned* rec = binnedC + (size_t)b * CAPC;
  int p = t;
  for (; p + 3072 < cnt; p += 4096) {
    unsigned a0 = rec[p], a1 = rec[p + 1024], a2 = rec[p + 2048], a3 = rec[p + 3072];
    float i0 = invdg[a0 & VMASK], i1 = invdg[a1 & VMASK];
    float i2 = invdg[a2 & VMASK], i3 = invdg[a3 & VMASK];
    atomicAdd(&n_l[a0 >> 18], 1); atomicAdd(&w_l[a0 >> 18], i0);
    atomicAdd(&n_l[a1 >> 18], 1); atomicAdd(&w_l[a1 >> 18], i1);
    atomicAdd(&n_l[a2 >> 18], 1); atomicAdd(&w_l[a2 >> 18], i2);
    atomicAdd(&n_l[a3 >> 18], 1); atomicAdd(&w_l[a3 >> 18], i3);
  }
  for (; p < cnt; p += 1024) {
    unsigned a0 = rec[p];
    atomicAdd(&n_l[a0 >> 18], 1);
    atomicAdd(&w_l[a0 >> 18], invdg[a0 & VMASK]);
  }
  __syncthreads();
  int e = (b << CSH) + t;
  if (e < N_E) wn[e] = make_float2(w_l[t], (float)n_l[t]);
}

// ---------------- P2: Wv, Sv, WvD ----------------
__global__ __launch_bounds__(1024) void k_p2(const unsigned* __restrict__ binnedR, const int* __restrict__ cntR,
                                             const float2* __restrict__ wn, const float* __restrict__ invdg,
                                             float* __restrict__ Wv, float* __restrict__ Sv,
                                             float* __restrict__ WvD) {
  __shared__ float W_l[512], S_l[512];
  int t = threadIdx.x, b = blockIdx.x;
  if (t < 512) { W_l[t] = 0.f; S_l[t] = 0.f; }
  __syncthreads();
  int cnt = cntR[b];
  const unsigned* rec = binnedR + (size_t)b * CAPR;
  int p = t;
  for (; p + 3072 < cnt; p += 4096) {
    unsigned a0 = rec[p], a1 = rec[p + 1024], a2 = rec[p + 2048], a3 = rec[p + 3072];
    float2 w0 = wn[a0 & VMASK], w1 = wn[a1 & VMASK], w2 = wn[a2 & VMASK], w3 = wn[a3 & VMASK];
    atomicAdd(&W_l[a0 >> 18], w0.x); atomicAdd(&S_l[a0 >> 18], w0.y);
    atomicAdd(&W_l[a1 >> 18], w1.x); atomicAdd(&S_l[a1 >> 18], w1.y);
    atomicAdd(&W_l[a2 >> 18], w2.x); atomicAdd(&S_l[a2 >> 18], w2.y);
    atomicAdd(&W_l[a3 >> 18], w3.x); atomicAdd(&S_l[a3 >> 18], w3.y);
  }
  for (; p < cnt; p += 1024) {
    unsigned a0 = rec[p];
    float2 w0 = wn[a0 & VMASK];
    atomicAdd(&W_l[a0 >> 18], w0.x); atomicAdd(&S_l[a0 >> 18], w0.y);
  }
  __syncthreads();
  if (t < 512) {
    int v = (b << RSH) + t;
    if (v < N_V) {
      float W = W_l[t];
      Wv[v] = W; Sv[v] = S_l[t]; WvD[v] = W * invdg[v];
    }
  }
}

// ---------------- P3: z[e] = sum WvD over edge members ----------------
__global__ __launch_bounds__(1024) void k_p3(const unsigned* __restrict__ binnedC, const int* __restrict__ cntC,
                                             const float* __restrict__ WvD, float* __restrict__ zM) {
  __shared__ float z_l[1024];
  int t = threadIdx.x, b = blockIdx.x;
  z_l[t] = 0.f;
  __syncthreads();
  int cnt = cntC[b];
  const unsigned* rec = binnedC + (size_t)b * CAPC;
  int p = t;
  for (; p + 3072 < cnt; p += 4096) {
    unsigned a0 = rec[p], a1 = rec[p + 1024], a2 = rec[p + 2048], a3 = rec[p + 3072];
    float v0 = WvD[a0 & VMASK], v1 = WvD[a1 & VMASK];
    float v2 = WvD[a2 & VMASK], v3 = WvD[a3 & VMASK];
    atomicAdd(&z_l[a0 >> 18], v0); atomicAdd(&z_l[a1 >> 18], v1);
    atomicAdd(&z_l[a2 >> 18], v2); atomicAdd(&z_l[a3 >> 18], v3);
  }
  for (; p < cnt; p += 1024) {
    unsigned a0 = rec[p];
    atomicAdd(&z_l[a0 >> 18], WvD[a0 & VMASK]);
  }
  __syncthreads();
  int e = (b << CSH) + t;
  if (e < N_E) zM[e] = z_l[t];
}

// ---------------- P4: Z2 (LDS) + 4 weighted X column-sums ----------------
__global__ __launch_bounds__(1024) void k_p4(const unsigned* __restrict__ binnedR, const int* __restrict__ cntR,
                                             const float* __restrict__ zM,
                                             const float* __restrict__ rdegf, const float* __restrict__ Wv,
                                             const float* __restrict__ Sv, const float* __restrict__ X,
                                             float* __restrict__ swg) {
  __shared__ float Z_l[512];
  __shared__ float swl[64];
  int t = threadIdx.x, b = blockIdx.x;
  if (t < 512) Z_l[t] = 0.f;
  if (t < 64) swl[t] = 0.f;
  __syncthreads();
  int cnt = cntR[b];
  const unsigned* rec = binnedR + (size_t)b * CAPR;
  int p = t;
  for (; p + 3072 < cnt; p += 4096) {
    unsigned a0 = rec[p], a1 = rec[p + 1024], a2 = rec[p + 2048], a3 = rec[p + 3072];
    float v0 = zM[a0 & VMASK], v1 = zM[a1 & VMASK];
    float v2 = zM[a2 & VMASK], v3 = zM[a3 & VMASK];
    atomicAdd(&Z_l[a0 >> 18], v0); atomicAdd(&Z_l[a1 >> 18], v1);
    atomicAdd(&Z_l[a2 >> 18], v2); atomicAdd(&Z_l[a3 >> 18], v3);
  }
  for (; p < cnt; p += 1024) {
    unsigned a0 = rec[p];
    atomicAdd(&Z_l[a0 >> 18], zM[a0 & VMASK]);
  }
  __syncthreads();
  {
    int tv = t >> 1, h = t & 1;         // thread = (vertex-in-bin, half-of-dims)
    int v = (b << RSH) + tv;
    float ps0[8] = {0,0,0,0,0,0,0,0}, ps1[8] = {0,0,0,0,0,0,0,0};
    float ps2[8] = {0,0,0,0,0,0,0,0}, ps3[8] = {0,0,0,0,0,0,0,0};
    if (v < N_V) {
      float w1 = Wv[v];
      float w2 = rdegf[v] + Sv[v];
      float w3 = w1 + Z_l[tv];
      const float* xp = X + (size_t)v * D_IN + h * 7;
#pragma unroll
      for (int j = 0; j < 7; j++) {
        float xv = xp[j];
        ps0[j] += xv; ps1[j] += w1 * xv; ps2[j] += w2 * xv; ps3[j] += w3 * xv;
      }
      if (h) { ps0[7] = 1.f; ps1[7] = w1; ps2[7] = w2; ps3[7] = w3; }  // weight totals
    }
#pragma unroll
    for (int j = 0; j < 8; j++) {
      float v0 = ps0[j], v1 = ps1[j], v2 = ps2[j], v3 = ps3[j];
#pragma unroll
      for (int off = 2; off < 64; off <<= 1) {   // butterfly over same-h lanes
        v0 += __shfl_xor(v0, off); v1 += __shfl_xor(v1, off);
        v2 += __shfl_xor(v2, off); v3 += __shfl_xor(v3, off);
      }
      int lane = t & 63;
      if (lane < 2) {                   // lane 0: h=0 sums, lane 1: h=1 sums
        int s = lane * 8 + j;
        atomicAdd(&swl[0 * 16 + s], v0);
        atomicAdd(&swl[1 * 16 + s], v1);
        atomicAdd(&swl[2 * 16 + s], v2);
        atomicAdd(&swl[3 * 16 + s], v3);
      }
    }
  }
  __syncthreads();
  if (t < 64) atomicAdd(&swg[t], swl[t]);
}

// ---------------- P5: project 4x14 sums through W0f, push Wl1, output heads ----------------
__global__ __launch_bounds__(128) void k_p5(const float* __restrict__ swg,
                                            const float* __restrict__ W0f, const float* __restrict__ b0f,
                                            const float* __restrict__ Wl1, const float* __restrict__ bl1,
                                            const float* __restrict__ Wo0, const float* __restrict__ bo0,
                                            const float* __restrict__ Wo1, const float* __restrict__ bo1,
                                            float* __restrict__ out) {
  __shared__ float swl[64];
  __shared__ float fA[128], fB[128], redl[128];
  int t = threadIdx.x;
  if (t < 64) swl[t] = swg[t];
  __syncthreads();
  {
    float a_ = 0.f, e_ = 0.f;
#pragma unroll
    for (int j = 0; j < D_IN; j++) {
      int s = j < 7 ? j : j + 1;        // swl layout: [0..6]=dims0-6, [8..14]=dims7-13, [15]=sum w
      float w0 = W0f[j * H + t];
      a_ += (swl[s] + swl[16 + s] + swl[48 + s]) * w0;   // cs0+cs1+cs3
      e_ += swl[32 + s] * w0;                            // cs2
    }
    float S0 = swl[15], S1 = swl[31], S2 = swl[47], S3 = swl[63];
    float bb_ = b0f[t];
    a_ += (S0 + S1 + S3) * bb_;
    e_ += S2 * bb_;
    fA[t] = a_;
    fB[t] = e_;
  }
  __syncthreads();
  {
    float sx = 0.f, se = 0.f;
    for (int k = 0; k < H; k++) {
      float wv = Wl1[k * H + t];
      sx += fA[k] * wv;
      se += fB[k] * wv;
    }
    float Q = swl[31];                  // sum_v Wv == qsum
    sx += ((float)N_V + Q) * bl1[t];
    se += (float)NNZ * bl1[t];
    redl[t] = sx * (1.f / (float)N_V) * Wo0[t] + se * (1.f / (float)N_E) * Wo1[t];
  }
  __syncthreads();
  for (int o = 64; o > 0; o >>= 1) {
    if (t < o) redl[t] += redl[t + o];
    __syncthreads();
  }
  if (t == 0) out[0] = redl[0] + bo0[0] + bo1[0];
}

extern "C" void kernel_launch(void* const* d_in, const int* in_sizes, int n_in,
                              void* d_out, int out_size, void* d_ws, size_t ws_size,
                              hipStream_t stream) {
  const float* x0in = (const float*)d_in[0];
  const int* rows   = (const int*)d_in[2];
  const int* cols   = (const int*)d_in[3];
  const float* W0   = (const float*)d_in[4];
  const float* b0   = (const float*)d_in[5];
  const float* Wl0  = (const float*)d_in[8];
  const float* bl0  = (const float*)d_in[9];
  const float* Wl1  = (const float*)d_in[10];
  const float* bl1  = (const float*)d_in[11];
  const float* Wo0  = (const float*)d_in[12];
  const float* bo0  = (const float*)d_in[13];
  const float* Wo1  = (const float*)d_in[14];
  const float* bo1  = (const float*)d_in[15];
  float* out = (float*)d_out;
  char* ws = (char*)d_ws;

  // ---- workspace layout (only [0, 4096) needs zeroing) ----
  int*      cntR    = (int*)(ws + 0);            // 196 ints (pad 1024)
  int*      cntC    = (int*)(ws + 1024);         // 196 ints (pad 1024)
  float*    swg     = (float*)(ws + 2048);       // 64 floats
  float*    W0f     = (float*)(ws + 4096);       // 7,168
  float*    b0f     = (float*)(ws + 11264);      // 512
  float*    invdg   = (float*)(ws + 12288);      // 400,000
  float*    rdegf   = (float*)(ws + 412288);     // 400,000
  float*    Wv      = (float*)(ws + 812288);     // 400,000
  float*    Sv      = (float*)(ws + 1212288);    // 400,000
  float*    WvD     = (float*)(ws + 1612288);    // 400,000
  float2*   wn      = (float2*)(ws + 2012288);   // 1,600,000
  float*    zM      = (float*)(ws + 3612288);    // 800,000
  unsigned* binnedR = (unsigned*)(ws + 4412288); // 196*6144*4 = 4,816,896
  unsigned* binnedC = (unsigned*)(ws + 9229184); // 4,816,896
  // total: 14,046,080 B

  hipMemsetAsync(ws, 0, 4096, stream);
  k_bin2<<<dim3(NB + D_IN + 1), dim3(1024), 0, stream>>>(rows, cols, W0, b0, Wl0, bl0,
                                                         W0f, b0f, binnedR, cntR, binnedC, cntC);
  k_p0<<<dim3(NB), dim3(1024), 0, stream>>>(binnedR, cntR, rdegf, invdg);
  k_p1<<<dim3(NB), dim3(1024), 0, stream>>>(binnedC, cntC, invdg, wn);
  k_p2<<<dim3(NB), dim3(1024), 0, stream>>>(binnedR, cntR, wn, invdg, Wv, Sv, WvD);
  k_p3<<<dim3(NB), dim3(1024), 0, stream>>>(binnedC, cntC, WvD, zM);
  k_p4<<<dim3(NB), dim3(1024), 0, stream>>>(binnedR, cntR, zM, rdegf, Wv, Sv, x0in, swg);
  k_p5<<<dim3(1), dim3(128), 0, stream>>>(swg, W0f, b0f, Wl1, bl1, Wo0, bo0, Wo1, bo1, out);
}